// Round 1
// 346.665 us; speedup vs baseline: 1.1785x; 1.1785x over previous
//
#include <hip/hip_runtime.h>
#include <hip/hip_bf16.h>
#include <type_traits>

#define DEVFN __device__ __forceinline__

typedef __attribute__((ext_vector_type(8))) short bfrag;   // 8 bf16 (4 VGPRs)
typedef __attribute__((ext_vector_type(4))) float facc4;   // 4 fp32 acc

DEVFN float lrelu(float v) { return (v >= 0.f) ? v : 0.2f * v; }

// packed bf16x2 (uint) -> 2 floats; elem0 = low 16 bits
DEVFN float2 bf2x2(unsigned u) {
  return make_float2(__uint_as_float(u << 16), __uint_as_float(u & 0xFFFF0000u));
}
DEVFN float bf1(unsigned short b) { return __uint_as_float(((unsigned)b) << 16); }
DEVFN unsigned short f2bf(float f) {
  __hip_bfloat16 h = __float2bfloat16(f);
  return *reinterpret_cast<unsigned short*>(&h);
}
DEVFN unsigned packbf2(float x, float y) {
  return (unsigned)f2bf(x) | ((unsigned)f2bf(y) << 16);
}

DEVFN float wave_sum(float v) {
#pragma unroll
  for (int o = 1; o < 64; o <<= 1) v += __shfl_xor(v, o, 64);
  return v;
}
DEVFN float wave_max(float v) {
#pragma unroll
  for (int o = 1; o < 64; o <<= 1) v = fmaxf(v, __shfl_xor(v, o, 64));
  return v;
}

// ---------------------------------------------------------------------------
// MFMA GEMM + fused escore + fused weight conversion.
// H[N][C] = X[N][128] @ W[128][C] (fp32 W staged to bf16-transposed LDS).
// A_FP32: read X as fp32 and convert in-register (layer 0, avoids conv pass).
// mfma_f32_16x16x32_bf16 layouts (m89): A[m=lane&15][k=quad*8+j],
// B[k][n=lane&15], D[row=quad*4+reg][col=lane&15].
// ---------------------------------------------------------------------------
template<int C, bool A_FP32>
__global__ __launch_bounds__(256) void gemm_mfma(const void* __restrict__ Xin,
                                                 const float* __restrict__ W,
                                                 const float* __restrict__ a_src,
                                                 const float* __restrict__ a_dst,
                                                 unsigned short* __restrict__ H,
                                                 float* __restrict__ es,
                                                 float* __restrict__ ed,
                                                 int N) {
  constexpr int K = 128;
  constexpr int LSTR = K + 8;
  constexpr int NT = C / 16;
  __shared__ unsigned short WsT[C * LSTR];

  const int t = threadIdx.x;
  // stage W (fp32 row-major [k][C]) -> WsT[c][k] bf16, transposed
  for (int i = t; i < K * C; i += 256) {
    int k = i / C;               // C is a power of two -> shift
    int c = i - k * C;
    WsT[c * LSTR + k] = f2bf(W[i]);
  }
  __syncthreads();

  const int wave = t >> 6;
  const int lane = t & 63;
  const int l15 = lane & 15;
  const int quad = lane >> 4;
  const int arow = blockIdx.x * 64 + wave * 16 + l15;
  const bool avalid = arow < N;

  facc4 acc[NT];
#pragma unroll
  for (int i = 0; i < NT; ++i) acc[i] = (facc4){0.f, 0.f, 0.f, 0.f};

#pragma unroll
  for (int ks = 0; ks < 4; ++ks) {
    bfrag a;
    if (A_FP32) {
      if (avalid) {
        const float* xp = (const float*)Xin + (size_t)arow * K + quad * 8 + ks * 32;
        float4 u = *(const float4*)xp;
        float4 v = *(const float4*)(xp + 4);
        a[0] = (short)f2bf(u.x); a[1] = (short)f2bf(u.y);
        a[2] = (short)f2bf(u.z); a[3] = (short)f2bf(u.w);
        a[4] = (short)f2bf(v.x); a[5] = (short)f2bf(v.y);
        a[6] = (short)f2bf(v.z); a[7] = (short)f2bf(v.w);
      } else {
        a = (bfrag){0, 0, 0, 0, 0, 0, 0, 0};
      }
    } else {
      // XB is NPAD-padded; padding rows produce garbage, guarded at writes
      const unsigned short* xp =
          (const unsigned short*)Xin + (size_t)arow * K + quad * 8 + ks * 32;
      a = *(const bfrag*)xp;
    }
#pragma unroll
    for (int ct = 0; ct < NT; ++ct) {
      bfrag b = *(const bfrag*)(&WsT[(ct * 16 + l15) * LSTR + ks * 32 + quad * 8]);
      acc[ct] = __builtin_amdgcn_mfma_f32_16x16x32_bf16(a, b, acc[ct], 0, 0, 0);
    }
  }

  float asv[NT], adv[NT];
#pragma unroll
  for (int ct = 0; ct < NT; ++ct) {
    asv[ct] = a_src[ct * 16 + l15];
    adv[ct] = a_dst[ct * 16 + l15];
  }

  const int orow0 = blockIdx.x * 64 + wave * 16 + quad * 4;
#pragma unroll
  for (int r = 0; r < 4; ++r) {
    const int orow = orow0 + r;
    float ps = 0.f, pd = 0.f;
#pragma unroll
    for (int ct = 0; ct < NT; ++ct) {
      if (orow < N) H[(size_t)orow * C + ct * 16 + l15] = f2bf(acc[ct][r]);
      ps += acc[ct][r] * asv[ct];
      pd += acc[ct][r] * adv[ct];
    }
#pragma unroll
    for (int msk = 1; msk < 16; msk <<= 1) {
      ps += __shfl_xor(ps, msk, 64);
      pd += __shfl_xor(pd, msk, 64);
    }
    if (l15 == 0 && orow < N) { es[orow] = ps; ed[orow] = pd; }
  }
}

// ---------------------------------------------------------------------------
// CSR build, u16 path: radix partition (bucket = dst>>9, <=128 buckets).
// Phase 1: per-block bucket histogram ONLY (no global DEG atomics — those
//          cost 51 MB of coherence write-back and 70 us in the prior rev).
// Phase 2: exact offsets via exclusive scan of the bucket-major matrix.
// Phase 3: place edges grouped by bucket (sequential full-line writes).
// Phase 4: one WG per bucket: LDS degree-count + LDS scan derives RP locally
//          (RP[n0+i] = bucket_start + excl_scan(deg_i)), then places COL.
//          COL region owned by one XCD (no write amp), zero global atomics.
// ---------------------------------------------------------------------------
__global__ void hist_only(const int* __restrict__ dst, int* __restrict__ hmat,
                          int E, int nbk, int chunk) {
  __shared__ int hist[4 * 128];              // 4-way wave replication
  const int t = threadIdx.x;
  for (int i = t; i < 4 * 128; i += 256) hist[i] = 0;
  __syncthreads();
  int* h = &hist[(t >> 6) << 7];
  const int e0 = blockIdx.x * chunk;
  const int e1 = min(E, e0 + chunk);
  for (int e = e0 + t; e < e1; e += 256) {
    atomicAdd(&h[dst[e] >> 9], 1);
  }
  __syncthreads();
  if (t < nbk)
    hmat[t * gridDim.x + blockIdx.x] =
        hist[t] + hist[t + 128] + hist[t + 256] + hist[t + 384];
}

__global__ void scan_partial(const int* __restrict__ in, int* __restrict__ csum, int n) {
  __shared__ int sh[256];
  int i = blockIdx.x * 256 + threadIdx.x;
  sh[threadIdx.x] = (i < n) ? in[i] : 0;
  __syncthreads();
  for (int o = 128; o > 0; o >>= 1) {
    if (threadIdx.x < o) sh[threadIdx.x] += sh[threadIdx.x + o];
    __syncthreads();
  }
  if (threadIdx.x == 0) csum[blockIdx.x] = sh[0];
}

__global__ void scan_chunks(int* __restrict__ csum, int nch) {
  __shared__ int sh[256];
  __shared__ int carry;
  if (threadIdx.x == 0) carry = 0;
  __syncthreads();
  for (int base = 0; base < nch; base += 256) {
    int i = base + threadIdx.x;
    int v = (i < nch) ? csum[i] : 0;
    sh[threadIdx.x] = v;
    __syncthreads();
    for (int o = 1; o < 256; o <<= 1) {
      int t = (threadIdx.x >= o) ? sh[threadIdx.x - o] : 0;
      __syncthreads();
      sh[threadIdx.x] += t;
      __syncthreads();
    }
    if (i < nch) csum[i] = carry + sh[threadIdx.x] - v;
    __syncthreads();
    if (threadIdx.x == 255) carry += sh[255];
    __syncthreads();
  }
}

// exclusive scan of DEG -> rp (+wp for fallback); rp[N]=E
__global__ void scan_final(const int* __restrict__ deg, const int* __restrict__ csum,
                           int* __restrict__ rp, int* __restrict__ wp, int N, int E) {
  __shared__ int sh[256];
  int i = blockIdx.x * 256 + threadIdx.x;
  int v = (i < N) ? deg[i] : 0;
  sh[threadIdx.x] = v;
  __syncthreads();
  for (int o = 1; o < 256; o <<= 1) {
    int t = (threadIdx.x >= o) ? sh[threadIdx.x - o] : 0;
    __syncthreads();
    sh[threadIdx.x] += t;
    __syncthreads();
  }
  if (i < N) {
    int r = csum[blockIdx.x] + sh[threadIdx.x] - v;
    rp[i] = r;
    wp[i] = r;
  }
  if (blockIdx.x == 0 && threadIdx.x == 0) rp[N] = E;
}

// generic exclusive scan -> out
__global__ void scan_final_excl(const int* __restrict__ in, const int* __restrict__ csum,
                                int* __restrict__ out, int n) {
  __shared__ int sh[256];
  int i = blockIdx.x * 256 + threadIdx.x;
  int v = (i < n) ? in[i] : 0;
  sh[threadIdx.x] = v;
  __syncthreads();
  for (int o = 1; o < 256; o <<= 1) {
    int t = (threadIdx.x >= o) ? sh[threadIdx.x - o] : 0;
    __syncthreads();
    sh[threadIdx.x] += t;
    __syncthreads();
  }
  if (i < n) out[i] = csum[blockIdx.x] + sh[threadIdx.x] - v;
}

__global__ void place_pass(const int* __restrict__ src, const int* __restrict__ dst,
                           const int* __restrict__ off, int2* __restrict__ be,
                           int E, int nbk, int chunk) {
  __shared__ int cur[128];
  const int t = threadIdx.x;
  if (t < nbk) cur[t] = off[t * gridDim.x + blockIdx.x];
  __syncthreads();
  const int e0 = blockIdx.x * chunk;
  const int e1 = min(E, e0 + chunk);
  for (int e = e0 + t; e < e1; e += 256) {
    int d = dst[e];
    int s = src[e];
    int p = atomicAdd(&cur[d >> 9], 1);
    be[p] = make_int2(s, d);
  }
}

// One WG per bucket of 512 dst nodes. Counts local degrees in LDS, scans
// them (pairwise Hillis-Steele over 256 pair-sums), derives RP from the
// bucket's global edge offset, then places COL. No global atomics anywhere.
__global__ void bucket_final(const int2* __restrict__ be, const int* __restrict__ off,
                             int* __restrict__ rp, unsigned short* __restrict__ col,
                             int E, int N, int nbk, int pblk) {
  __shared__ int cur[512];
  __shared__ int ps[256];
  const int b = blockIdx.x;
  const int n0 = b << 9;
  const int cnt = min(512, N - n0);
  const int t = threadIdx.x;
  for (int i = t; i < cnt; i += 256) cur[i] = 0;
  __syncthreads();
  const int e0 = off[b * pblk];
  const int e1 = (b + 1 < nbk) ? off[(b + 1) * pblk] : E;
  // phase A: local degree histogram
  for (int e = e0 + t; e < e1; e += 256) {
    int2 sd = be[e];
    atomicAdd(&cur[sd.y - n0], 1);
  }
  __syncthreads();
  // phase B: exclusive scan of cur[0..cnt) (pairs per thread)
  const int i0 = 2 * t, i1 = 2 * t + 1;
  const int v0 = (i0 < cnt) ? cur[i0] : 0;
  const int v1 = (i1 < cnt) ? cur[i1] : 0;
  ps[t] = v0 + v1;
  __syncthreads();
  for (int o = 1; o < 256; o <<= 1) {
    int u = (t >= o) ? ps[t - o] : 0;
    __syncthreads();
    ps[t] += u;
    __syncthreads();
  }
  const int base = e0 + ps[t] - (v0 + v1);   // exclusive base of pair
  if (i0 < cnt) { rp[n0 + i0] = base;      cur[i0] = base; }
  if (i1 < cnt) { rp[n0 + i1] = base + v0; cur[i1] = base + v0; }
  if (b == nbk - 1 && t == 0) rp[N] = E;
  __syncthreads();
  // phase C: place
  for (int e = e0 + t; e < e1; e += 256) {
    int2 sd = be[e];
    int p = atomicAdd(&cur[sd.y - n0], 1);
    col[p] = (unsigned short)sd.x;
  }
}

// Fallback (N > 65535): ranged multi-pass scatter with int COL.
__global__ void csr_scatter_ranged(const int* __restrict__ src,
                                   const int* __restrict__ dst,
                                   int* __restrict__ wp, int* __restrict__ col,
                                   int E, int range, int npass) {
  const int stride = gridDim.x * blockDim.x;
  const int gid = blockIdx.x * blockDim.x + threadIdx.x;
  for (int pass = 0; pass < npass; ++pass) {
    const int lo = pass * range;
    const int hi = lo + range;
    for (int e = gid; e < E; e += stride) {
      int d = dst[e];
      if (d >= lo && d < hi) {
        int p = atomicAdd(wp + d, 1);
        col[p] = src[e];
      }
    }
  }
}

__global__ void csr_count(const int* __restrict__ dst, int* __restrict__ deg, int E) {
  int e = blockIdx.x * blockDim.x + threadIdx.x;
  if (e < E) atomicAdd(deg + dst[e], 1);
}

// ---------------------------------------------------------------------------
// Fully fused GAT edge stage (softmax in registers + gather via __shfl
// broadcast). 8-edge batches -> 8 independent H loads in flight per wave.
// ---------------------------------------------------------------------------
template<bool RELU, bool OUT_BF16, typename IT>
__global__ void gat_fused128(const int* __restrict__ row_ptr,
                             const IT* __restrict__ col,
                             const float* __restrict__ es,
                             const float* __restrict__ ed,
                             const unsigned short* __restrict__ H,
                             const float* __restrict__ bias,
                             void* __restrict__ outX, int N) {
  const int lane = threadIdx.x & 63;
  const int n = blockIdx.x * (blockDim.x >> 6) + (threadIdx.x >> 6);
  if (n >= N) return;

  const int k0 = row_ptr[n];
  const int k1 = row_ptr[n + 1];
  const int deg = k1 - k0;
  const float edd = ed[n];
  const float self_lg = lrelu(es[n] + edd);

  const unsigned* Hp = (const unsigned*)H;   // bf16x2 per lane
  float ax0 = 0.f, ay0 = 0.f, ax1 = 0.f, ay1 = 0.f;
  float den, sp;

  if (deg <= 64) {
    int k = k0 + lane;
    bool act = (k < k1);
    int c = act ? (int)col[k] : 0;
    float lg = act ? lrelu(es[c] + edd) : -3.0e38f;
    float m = fmaxf(wave_max(lg), self_lg);
    float p = act ? __expf(lg - m) : 0.f;
    sp = __expf(self_lg - m);
    den = wave_sum(p) + sp;
    int j = 0;
    for (; j + 8 <= deg; j += 8) {
      int ss[8];
      float pp[8];
      unsigned uu[8];
#pragma unroll
      for (int q = 0; q < 8; ++q) {
        ss[q] = __shfl(c, j + q);
        pp[q] = __shfl(p, j + q);
      }
#pragma unroll
      for (int q = 0; q < 8; ++q) uu[q] = Hp[(size_t)ss[q] * 64 + lane];
#pragma unroll
      for (int q = 0; q < 8; ++q) {
        float2 h = bf2x2(uu[q]);
        if (q & 1) { ax1 += pp[q] * h.x; ay1 += pp[q] * h.y; }
        else       { ax0 += pp[q] * h.x; ay0 += pp[q] * h.y; }
      }
    }
    for (; j < deg; ++j) {
      int s = __shfl(c, j);
      float pj = __shfl(p, j);
      float2 h = bf2x2(Hp[(size_t)s * 64 + lane]);
      ax0 += pj * h.x; ay0 += pj * h.y;
    }
  } else {
    float mloc = self_lg;
    for (int base = k0; base < k1; base += 64) {
      int k = base + lane;
      if (k < k1) mloc = fmaxf(mloc, lrelu(es[(int)col[k]] + edd));
    }
    float m = wave_max(mloc);
    sp = __expf(self_lg - m);
    den = sp;
    for (int base = k0; base < k1; base += 64) {
      int k = base + lane;
      bool act = (k < k1);
      int c = act ? (int)col[k] : 0;
      float p = act ? __expf(lrelu(es[c] + edd) - m) : 0.f;
      den += wave_sum(p);
      int len = min(64, k1 - base);
      for (int j = 0; j < len; ++j) {
        int s = __shfl(c, j);
        float pj = __shfl(p, j);
        float2 h = bf2x2(Hp[(size_t)s * 64 + lane]);
        ax0 += pj * h.x; ay0 += pj * h.y;
      }
    }
  }

  float2 hv = bf2x2(Hp[(size_t)n * 64 + lane]);
  ax0 += sp * hv.x; ay0 += sp * hv.y;
  float inv = 1.f / den;
  float2 bv = ((const float2*)bias)[lane];
  float vx = (ax0 + ax1) * inv + bv.x;
  float vy = (ay0 + ay1) * inv + bv.y;
  if (RELU) { vx = fmaxf(vx, 0.f); vy = fmaxf(vy, 0.f); }
  if (OUT_BF16)
    ((unsigned*)outX)[(size_t)n * 64 + lane] = packbf2(vx, vy);
  else
    ((float2*)outX)[(size_t)n * 64 + lane] = make_float2(vx, vy);
}

template<bool RELU, typename IT>
__global__ void gat_fused64(const int* __restrict__ row_ptr,
                            const IT* __restrict__ col,
                            const float* __restrict__ es,
                            const float* __restrict__ ed,
                            const unsigned short* __restrict__ H,
                            const float* __restrict__ bias,
                            float* __restrict__ outX, int N) {
  const int lane = threadIdx.x & 63;
  const int n = blockIdx.x * (blockDim.x >> 6) + (threadIdx.x >> 6);
  if (n >= N) return;

  const int k0 = row_ptr[n];
  const int k1 = row_ptr[n + 1];
  const int deg = k1 - k0;
  const float edd = ed[n];
  const float self_lg = lrelu(es[n] + edd);

  float a0 = 0.f, a1 = 0.f;
  float den, sp;

  if (deg <= 64) {
    int k = k0 + lane;
    bool act = (k < k1);
    int c = act ? (int)col[k] : 0;
    float lg = act ? lrelu(es[c] + edd) : -3.0e38f;
    float m = fmaxf(wave_max(lg), self_lg);
    float p = act ? __expf(lg - m) : 0.f;
    sp = __expf(self_lg - m);
    den = wave_sum(p) + sp;
    int j = 0;
    for (; j + 8 <= deg; j += 8) {
      int ss[8];
      float pp[8];
      unsigned short uu[8];
#pragma unroll
      for (int q = 0; q < 8; ++q) {
        ss[q] = __shfl(c, j + q);
        pp[q] = __shfl(p, j + q);
      }
#pragma unroll
      for (int q = 0; q < 8; ++q) uu[q] = H[(size_t)ss[q] * 64 + lane];
#pragma unroll
      for (int q = 0; q < 8; ++q) {
        if (q & 1) a1 += pp[q] * bf1(uu[q]);
        else       a0 += pp[q] * bf1(uu[q]);
      }
    }
    for (; j < deg; ++j) {
      int s = __shfl(c, j);
      float pj = __shfl(p, j);
      a0 += pj * bf1(H[(size_t)s * 64 + lane]);
    }
  } else {
    float mloc = self_lg;
    for (int base = k0; base < k1; base += 64) {
      int k = base + lane;
      if (k < k1) mloc = fmaxf(mloc, lrelu(es[(int)col[k]] + edd));
    }
    float m = wave_max(mloc);
    sp = __expf(self_lg - m);
    den = sp;
    for (int base = k0; base < k1; base += 64) {
      int k = base + lane;
      bool act = (k < k1);
      int c = act ? (int)col[k] : 0;
      float p = act ? __expf(lrelu(es[c] + edd) - m) : 0.f;
      den += wave_sum(p);
      int len = min(64, k1 - base);
      for (int j = 0; j < len; ++j) {
        int s = __shfl(c, j);
        float pj = __shfl(p, j);
        a0 += pj * bf1(H[(size_t)s * 64 + lane]);
      }
    }
  }

  a0 += sp * bf1(H[(size_t)n * 64 + lane]);
  float v = (a0 + a1) / den + bias[lane];
  if (RELU) v = fmaxf(v, 0.f);
  outX[(size_t)n * 64 + lane] = v;
}

// ---------------------------------------------------------------------------

extern "C" void kernel_launch(void* const* d_in, const int* in_sizes, int n_in,
                              void* d_out, int out_size, void* d_ws, size_t ws_size,
                              hipStream_t stream) {
  const int C_HID = in_sizes[3];            // 128
  const int C_FIN = in_sizes[11];           // 64
  const int C_IN  = in_sizes[2] / C_HID;    // 128
  const int N     = in_sizes[0] / C_IN;     // 50000
  const int E     = in_sizes[1] / 2;        // 1.6M
  const int NPAD  = ((N + 63) / 64) * 64;

  const float* x = (const float*)d_in[0];
  const int* ei  = (const int*)d_in[1];
  const int* src = ei;
  const int* dst = ei + E;

  const float* W0  = (const float*)d_in[2];
  const float* as0 = (const float*)d_in[3];
  const float* ad0 = (const float*)d_in[4];
  const float* b0  = (const float*)d_in[5];
  const float* W1  = (const float*)d_in[6];
  const float* as1 = (const float*)d_in[7];
  const float* ad1 = (const float*)d_in[8];
  const float* b1  = (const float*)d_in[9];
  const float* W2  = (const float*)d_in[10];
  const float* as2 = (const float*)d_in[11];
  const float* ad2 = (const float*)d_in[12];
  const float* b2  = (const float*)d_in[13];

  // Workspace layout (256B aligned)
  char* base = (char*)d_ws;
  size_t off = 0;
  auto alloc = [&](size_t bytes) -> char* {
    char* p = base + off;
    off = (off + bytes + 255) & ~((size_t)255);
    return p;
  };
  const int PBLK = 512;                     // partition blocks
  const int NBK  = (N + 511) >> 9;          // buckets of 512 dst nodes (<=128)
  const int M    = NBK * PBLK;              // offset-matrix size
  const int NCH  = (N + 255) / 256;
  const int MCH  = (M + 255) / 256;
  const int SCH  = (NCH > MCH ? NCH : MCH);

  unsigned short* XB  = (unsigned short*)alloc((size_t)NPAD * C_HID * 2);
  unsigned short* H   = (unsigned short*)alloc((size_t)N * C_HID * 2);
  float* ES    = (float*)alloc((size_t)N * sizeof(float));
  float* ED    = (float*)alloc((size_t)N * sizeof(float));
  int*   RP    = (int*)alloc((size_t)(N + 1) * sizeof(int));
  int*   WP    = (int*)alloc((size_t)N * sizeof(int));
  void*  COL   = (void*)alloc((size_t)E * sizeof(int));   // u16 uses half
  int*   DEG   = (int*)alloc((size_t)N * sizeof(int));
  int*   CSUM  = (int*)alloc((size_t)SCH * sizeof(int));
  int*   HMAT  = (int*)alloc((size_t)M * sizeof(int));
  int*   OFF   = (int*)alloc((size_t)M * sizeof(int));
  int2*  BE    = (int2*)alloc((size_t)E * sizeof(int2));
  (void)ws_size;

  const int wgrid = (N + 3) / 4;
  const int mgrid = NPAD / 64;
  const bool u16 = (N <= 65535);

  // ---- CSR build ----
  if (u16) {
    const int CHUNK = (E + PBLK - 1) / PBLK;
    hist_only<<<PBLK, 256, 0, stream>>>(dst, HMAT, E, NBK, CHUNK);
    scan_partial<<<MCH, 256, 0, stream>>>(HMAT, CSUM, M);
    scan_chunks<<<1, 256, 0, stream>>>(CSUM, MCH);
    scan_final_excl<<<MCH, 256, 0, stream>>>(HMAT, CSUM, OFF, M);
    place_pass<<<PBLK, 256, 0, stream>>>(src, dst, OFF, BE, E, NBK, CHUNK);
    bucket_final<<<NBK, 256, 0, stream>>>(BE, OFF, RP, (unsigned short*)COL,
                                          E, N, NBK, PBLK);
  } else {
    hipMemsetAsync(DEG, 0, (size_t)N * sizeof(int), stream);
    const int ET256 = (E + 255) / 256;
    csr_count<<<ET256, 256, 0, stream>>>(dst, DEG, E);
    scan_partial<<<NCH, 256, 0, stream>>>(DEG, CSUM, N);
    scan_chunks<<<1, 256, 0, stream>>>(CSUM, NCH);
    scan_final<<<NCH, 256, 0, stream>>>(DEG, CSUM, RP, WP, N, E);
    const int NPASS = 8;
    const int range = (N + NPASS - 1) / NPASS;
    csr_scatter_ranged<<<2048, 256, 0, stream>>>(src, dst, WP, (int*)COL, E,
                                                 range, NPASS);
  }

  auto run_layers = [&](auto* col) {
    using IT = typename std::remove_pointer<decltype(col)>::type;
    // ---- Layer 0: x(fp32) -> H(+es/ed) -> XB (relu, bf16) ----
    gemm_mfma<128, true><<<mgrid, 256, 0, stream>>>(x, W0, as0, ad0, H, ES, ED, N);
    gat_fused128<true, true, IT><<<wgrid, 256, 0, stream>>>(RP, col, ES, ED, H, b0, XB, N);
    // ---- Layer 1: XB -> H(+es/ed) -> XB (relu, bf16) ----
    gemm_mfma<128, false><<<mgrid, 256, 0, stream>>>(XB, W1, as1, ad1, H, ES, ED, N);
    gat_fused128<true, true, IT><<<wgrid, 256, 0, stream>>>(RP, col, ES, ED, H, b1, XB, N);
    // ---- Layer 2: XB -> H(+es/ed) -> d_out (no relu, fp32) ----
    gemm_mfma<64, false><<<mgrid, 256, 0, stream>>>(XB, W2, as2, ad2, H, ES, ED, N);
    gat_fused64<false, IT><<<wgrid, 256, 0, stream>>>(RP, col, ES, ED, H, b2,
                                                      (float*)d_out, N);
  };

  if (u16) run_layers((unsigned short*)COL);
  else     run_layers((int*)COL);
  (void)out_size; (void)n_in;
}

// Round 2
// 340.805 us; speedup vs baseline: 1.1987x; 1.0172x over previous
//
#include <hip/hip_runtime.h>
#include <hip/hip_bf16.h>
#include <type_traits>

#define DEVFN __device__ __forceinline__

typedef __attribute__((ext_vector_type(8))) short bfrag;   // 8 bf16 (4 VGPRs)
typedef __attribute__((ext_vector_type(4))) float facc4;   // 4 fp32 acc

DEVFN float lrelu(float v) { return (v >= 0.f) ? v : 0.2f * v; }

// packed bf16x2 (uint) -> 2 floats; elem0 = low 16 bits
DEVFN float2 bf2x2(unsigned u) {
  return make_float2(__uint_as_float(u << 16), __uint_as_float(u & 0xFFFF0000u));
}
DEVFN float bf1(unsigned short b) { return __uint_as_float(((unsigned)b) << 16); }
DEVFN unsigned short f2bf(float f) {
  __hip_bfloat16 h = __float2bfloat16(f);
  return *reinterpret_cast<unsigned short*>(&h);
}
DEVFN unsigned packbf2(float x, float y) {
  return (unsigned)f2bf(x) | ((unsigned)f2bf(y) << 16);
}

DEVFN float wave_sum(float v) {
#pragma unroll
  for (int o = 1; o < 64; o <<= 1) v += __shfl_xor(v, o, 64);
  return v;
}
DEVFN float wave_max(float v) {
#pragma unroll
  for (int o = 1; o < 64; o <<= 1) v = fmaxf(v, __shfl_xor(v, o, 64));
  return v;
}

// wave-uniform lane broadcast -> SGPR (readlane; index must be uniform).
// Replaces __shfl's ds_bpermute + VGPR addr math with SALU-side scalars.
DEVFN int rdl_i(int v, int l) { return __builtin_amdgcn_readlane(v, l); }
DEVFN float rdl_f(float v, int l) {
  return __int_as_float(__builtin_amdgcn_readlane(__float_as_int(v), l));
}

// ---------------------------------------------------------------------------
// MFMA GEMM + fused escore + fused weight conversion.
// H[N][C] = X[N][128] @ W[128][C] (fp32 W staged to bf16-transposed LDS).
// A_FP32: read X as fp32 and convert in-register (layer 0, avoids conv pass).
// mfma_f32_16x16x32_bf16 layouts (m89): A[m=lane&15][k=quad*8+j],
// B[k][n=lane&15], D[row=quad*4+reg][col=lane&15].
// ---------------------------------------------------------------------------
template<int C, bool A_FP32>
__global__ __launch_bounds__(256) void gemm_mfma(const void* __restrict__ Xin,
                                                 const float* __restrict__ W,
                                                 const float* __restrict__ a_src,
                                                 const float* __restrict__ a_dst,
                                                 unsigned short* __restrict__ H,
                                                 float* __restrict__ es,
                                                 float* __restrict__ ed,
                                                 int N) {
  constexpr int K = 128;
  constexpr int LSTR = K + 8;
  constexpr int NT = C / 16;
  __shared__ unsigned short WsT[C * LSTR];

  const int t = threadIdx.x;
  // stage W (fp32 row-major [k][C]) -> WsT[c][k] bf16, transposed
  for (int i = t; i < K * C; i += 256) {
    int k = i / C;               // C is a power of two -> shift
    int c = i - k * C;
    WsT[c * LSTR + k] = f2bf(W[i]);
  }
  __syncthreads();

  const int wave = t >> 6;
  const int lane = t & 63;
  const int l15 = lane & 15;
  const int quad = lane >> 4;
  const int arow = blockIdx.x * 64 + wave * 16 + l15;
  const bool avalid = arow < N;

  facc4 acc[NT];
#pragma unroll
  for (int i = 0; i < NT; ++i) acc[i] = (facc4){0.f, 0.f, 0.f, 0.f};

#pragma unroll
  for (int ks = 0; ks < 4; ++ks) {
    bfrag a;
    if (A_FP32) {
      if (avalid) {
        const float* xp = (const float*)Xin + (size_t)arow * K + quad * 8 + ks * 32;
        float4 u = *(const float4*)xp;
        float4 v = *(const float4*)(xp + 4);
        a[0] = (short)f2bf(u.x); a[1] = (short)f2bf(u.y);
        a[2] = (short)f2bf(u.z); a[3] = (short)f2bf(u.w);
        a[4] = (short)f2bf(v.x); a[5] = (short)f2bf(v.y);
        a[6] = (short)f2bf(v.z); a[7] = (short)f2bf(v.w);
      } else {
        a = (bfrag){0, 0, 0, 0, 0, 0, 0, 0};
      }
    } else {
      // XB is NPAD-padded; padding rows produce garbage, guarded at writes
      const unsigned short* xp =
          (const unsigned short*)Xin + (size_t)arow * K + quad * 8 + ks * 32;
      a = *(const bfrag*)xp;
    }
#pragma unroll
    for (int ct = 0; ct < NT; ++ct) {
      bfrag b = *(const bfrag*)(&WsT[(ct * 16 + l15) * LSTR + ks * 32 + quad * 8]);
      acc[ct] = __builtin_amdgcn_mfma_f32_16x16x32_bf16(a, b, acc[ct], 0, 0, 0);
    }
  }

  float asv[NT], adv[NT];
#pragma unroll
  for (int ct = 0; ct < NT; ++ct) {
    asv[ct] = a_src[ct * 16 + l15];
    adv[ct] = a_dst[ct * 16 + l15];
  }

  const int orow0 = blockIdx.x * 64 + wave * 16 + quad * 4;
#pragma unroll
  for (int r = 0; r < 4; ++r) {
    const int orow = orow0 + r;
    float ps = 0.f, pd = 0.f;
#pragma unroll
    for (int ct = 0; ct < NT; ++ct) {
      if (orow < N) H[(size_t)orow * C + ct * 16 + l15] = f2bf(acc[ct][r]);
      ps += acc[ct][r] * asv[ct];
      pd += acc[ct][r] * adv[ct];
    }
#pragma unroll
    for (int msk = 1; msk < 16; msk <<= 1) {
      ps += __shfl_xor(ps, msk, 64);
      pd += __shfl_xor(pd, msk, 64);
    }
    if (l15 == 0 && orow < N) { es[orow] = ps; ed[orow] = pd; }
  }
}

// ---------------------------------------------------------------------------
// CSR build, u16 path: radix partition (bucket = dst>>9, <=128 buckets).
// Phase 1: per-block bucket histogram ONLY (no global DEG atomics).
// Phase 2: exact offsets via exclusive scan of the bucket-major matrix.
// Phase 3: place edges grouped by bucket (sequential full-line writes).
// Phase 4: one WG per bucket: LDS degree-count + LDS scan derives RP locally,
//          then places COL. Zero global atomics.
// ---------------------------------------------------------------------------
__global__ void hist_only(const int* __restrict__ dst, int* __restrict__ hmat,
                          int E, int nbk, int chunk) {
  __shared__ int hist[4 * 128];              // 4-way wave replication
  const int t = threadIdx.x;
  for (int i = t; i < 4 * 128; i += 256) hist[i] = 0;
  __syncthreads();
  int* h = &hist[(t >> 6) << 7];
  const int e0 = blockIdx.x * chunk;
  const int e1 = min(E, e0 + chunk);
  for (int e = e0 + t; e < e1; e += 256) {
    atomicAdd(&h[dst[e] >> 9], 1);
  }
  __syncthreads();
  if (t < nbk)
    hmat[t * gridDim.x + blockIdx.x] =
        hist[t] + hist[t + 128] + hist[t + 256] + hist[t + 384];
}

__global__ void scan_partial(const int* __restrict__ in, int* __restrict__ csum, int n) {
  __shared__ int sh[256];
  int i = blockIdx.x * 256 + threadIdx.x;
  sh[threadIdx.x] = (i < n) ? in[i] : 0;
  __syncthreads();
  for (int o = 128; o > 0; o >>= 1) {
    if (threadIdx.x < o) sh[threadIdx.x] += sh[threadIdx.x + o];
    __syncthreads();
  }
  if (threadIdx.x == 0) csum[blockIdx.x] = sh[0];
}

__global__ void scan_chunks(int* __restrict__ csum, int nch) {
  __shared__ int sh[256];
  __shared__ int carry;
  if (threadIdx.x == 0) carry = 0;
  __syncthreads();
  for (int base = 0; base < nch; base += 256) {
    int i = base + threadIdx.x;
    int v = (i < nch) ? csum[i] : 0;
    sh[threadIdx.x] = v;
    __syncthreads();
    for (int o = 1; o < 256; o <<= 1) {
      int t = (threadIdx.x >= o) ? sh[threadIdx.x - o] : 0;
      __syncthreads();
      sh[threadIdx.x] += t;
      __syncthreads();
    }
    if (i < nch) csum[i] = carry + sh[threadIdx.x] - v;
    __syncthreads();
    if (threadIdx.x == 255) carry += sh[255];
    __syncthreads();
  }
}

// exclusive scan of DEG -> rp (+wp for fallback); rp[N]=E
__global__ void scan_final(const int* __restrict__ deg, const int* __restrict__ csum,
                           int* __restrict__ rp, int* __restrict__ wp, int N, int E) {
  __shared__ int sh[256];
  int i = blockIdx.x * 256 + threadIdx.x;
  int v = (i < N) ? deg[i] : 0;
  sh[threadIdx.x] = v;
  __syncthreads();
  for (int o = 1; o < 256; o <<= 1) {
    int t = (threadIdx.x >= o) ? sh[threadIdx.x - o] : 0;
    __syncthreads();
    sh[threadIdx.x] += t;
    __syncthreads();
  }
  if (i < N) {
    int r = csum[blockIdx.x] + sh[threadIdx.x] - v;
    rp[i] = r;
    wp[i] = r;
  }
  if (blockIdx.x == 0 && threadIdx.x == 0) rp[N] = E;
}

// generic exclusive scan -> out
__global__ void scan_final_excl(const int* __restrict__ in, const int* __restrict__ csum,
                                int* __restrict__ out, int n) {
  __shared__ int sh[256];
  int i = blockIdx.x * 256 + threadIdx.x;
  int v = (i < n) ? in[i] : 0;
  sh[threadIdx.x] = v;
  __syncthreads();
  for (int o = 1; o < 256; o <<= 1) {
    int t = (threadIdx.x >= o) ? sh[threadIdx.x - o] : 0;
    __syncthreads();
    sh[threadIdx.x] += t;
    __syncthreads();
  }
  if (i < n) out[i] = csum[blockIdx.x] + sh[threadIdx.x] - v;
}

__global__ void place_pass(const int* __restrict__ src, const int* __restrict__ dst,
                           const int* __restrict__ off, int2* __restrict__ be,
                           int E, int nbk, int chunk) {
  __shared__ int cur[128];
  const int t = threadIdx.x;
  if (t < nbk) cur[t] = off[t * gridDim.x + blockIdx.x];
  __syncthreads();
  const int e0 = blockIdx.x * chunk;
  const int e1 = min(E, e0 + chunk);
  for (int e = e0 + t; e < e1; e += 256) {
    int d = dst[e];
    int s = src[e];
    int p = atomicAdd(&cur[d >> 9], 1);
    be[p] = make_int2(s, d);
  }
}

// One WG per bucket of 512 dst nodes. Counts local degrees in LDS, scans
// them (pairwise Hillis-Steele over 256 pair-sums), derives RP from the
// bucket's global edge offset, then places COL. No global atomics anywhere.
__global__ void bucket_final(const int2* __restrict__ be, const int* __restrict__ off,
                             int* __restrict__ rp, unsigned short* __restrict__ col,
                             int E, int N, int nbk, int pblk) {
  __shared__ int cur[512];
  __shared__ int ps[256];
  const int b = blockIdx.x;
  const int n0 = b << 9;
  const int cnt = min(512, N - n0);
  const int t = threadIdx.x;
  for (int i = t; i < cnt; i += 256) cur[i] = 0;
  __syncthreads();
  const int e0 = off[b * pblk];
  const int e1 = (b + 1 < nbk) ? off[(b + 1) * pblk] : E;
  // phase A: local degree histogram
  for (int e = e0 + t; e < e1; e += 256) {
    int2 sd = be[e];
    atomicAdd(&cur[sd.y - n0], 1);
  }
  __syncthreads();
  // phase B: exclusive scan of cur[0..cnt) (pairs per thread)
  const int i0 = 2 * t, i1 = 2 * t + 1;
  const int v0 = (i0 < cnt) ? cur[i0] : 0;
  const int v1 = (i1 < cnt) ? cur[i1] : 0;
  ps[t] = v0 + v1;
  __syncthreads();
  for (int o = 1; o < 256; o <<= 1) {
    int u = (t >= o) ? ps[t - o] : 0;
    __syncthreads();
    ps[t] += u;
    __syncthreads();
  }
  const int base = e0 + ps[t] - (v0 + v1);   // exclusive base of pair
  if (i0 < cnt) { rp[n0 + i0] = base;      cur[i0] = base; }
  if (i1 < cnt) { rp[n0 + i1] = base + v0; cur[i1] = base + v0; }
  if (b == nbk - 1 && t == 0) rp[N] = E;
  __syncthreads();
  // phase C: place
  for (int e = e0 + t; e < e1; e += 256) {
    int2 sd = be[e];
    int p = atomicAdd(&cur[sd.y - n0], 1);
    col[p] = (unsigned short)sd.x;
  }
}

// Fallback (N > 65535): ranged multi-pass scatter with int COL.
__global__ void csr_scatter_ranged(const int* __restrict__ src,
                                   const int* __restrict__ dst,
                                   int* __restrict__ wp, int* __restrict__ col,
                                   int E, int range, int npass) {
  const int stride = gridDim.x * blockDim.x;
  const int gid = blockIdx.x * blockDim.x + threadIdx.x;
  for (int pass = 0; pass < npass; ++pass) {
    const int lo = pass * range;
    const int hi = lo + range;
    for (int e = gid; e < E; e += stride) {
      int d = dst[e];
      if (d >= lo && d < hi) {
        int p = atomicAdd(wp + d, 1);
        col[p] = src[e];
      }
    }
  }
}

__global__ void csr_count(const int* __restrict__ dst, int* __restrict__ deg, int E) {
  int e = blockIdx.x * blockDim.x + threadIdx.x;
  if (e < E) atomicAdd(deg + dst[e], 1);
}

// ---------------------------------------------------------------------------
// Fully fused GAT edge stage. Softmax in registers; per-edge broadcast of
// (src,weight) via v_readlane (uniform index) -> SGPR, so the H-row gather
// compiles to SALU address + global_load with scalar base (no per-edge
// 64-bit VGPR address math, no ds_bpermute).
// ---------------------------------------------------------------------------
template<bool RELU, bool OUT_BF16, typename IT>
__global__ void gat_fused128(const int* __restrict__ row_ptr,
                             const IT* __restrict__ col,
                             const float* __restrict__ es,
                             const float* __restrict__ ed,
                             const unsigned short* __restrict__ H,
                             const float* __restrict__ bias,
                             void* __restrict__ outX, int N) {
  const int lane = threadIdx.x & 63;
  const int n = blockIdx.x * (blockDim.x >> 6) + (threadIdx.x >> 6);
  if (n >= N) return;

  const int k0 = row_ptr[n];
  const int k1 = row_ptr[n + 1];
  const int deg = k1 - k0;
  const float edd = ed[n];
  const float self_lg = lrelu(es[n] + edd);

  const unsigned* Hp = (const unsigned*)H;   // bf16x2 per lane
  float ax0 = 0.f, ay0 = 0.f, ax1 = 0.f, ay1 = 0.f;
  float den, sp;

  if (deg <= 64) {
    int k = k0 + lane;
    bool act = (k < k1);
    int c = act ? (int)col[k] : 0;
    float lg = act ? lrelu(es[c] + edd) : -3.0e38f;
    float m = fmaxf(wave_max(lg), self_lg);
    float p = act ? __expf(lg - m) : 0.f;
    sp = __expf(self_lg - m);
    den = wave_sum(p) + sp;
    int j = 0;
    for (; j + 8 <= deg; j += 8) {
      const unsigned* rp_[8];
      float pp[8];
      unsigned uu[8];
#pragma unroll
      for (int q = 0; q < 8; ++q) {
        rp_[q] = Hp + ((size_t)rdl_i(c, j + q) << 6);
        pp[q] = rdl_f(p, j + q);
      }
#pragma unroll
      for (int q = 0; q < 8; ++q) uu[q] = rp_[q][lane];
#pragma unroll
      for (int q = 0; q < 8; ++q) {
        float2 h = bf2x2(uu[q]);
        if (q & 1) { ax1 += pp[q] * h.x; ay1 += pp[q] * h.y; }
        else       { ax0 += pp[q] * h.x; ay0 += pp[q] * h.y; }
      }
    }
    for (; j < deg; ++j) {
      int s = rdl_i(c, j);
      float pj = rdl_f(p, j);
      float2 h = bf2x2(Hp[((size_t)s << 6) + lane]);
      ax0 += pj * h.x; ay0 += pj * h.y;
    }
  } else {
    float mloc = self_lg;
    for (int base = k0; base < k1; base += 64) {
      int k = base + lane;
      if (k < k1) mloc = fmaxf(mloc, lrelu(es[(int)col[k]] + edd));
    }
    float m = wave_max(mloc);
    sp = __expf(self_lg - m);
    den = sp;
    for (int base = k0; base < k1; base += 64) {
      int k = base + lane;
      bool act = (k < k1);
      int c = act ? (int)col[k] : 0;
      float p = act ? __expf(lrelu(es[c] + edd) - m) : 0.f;
      den += wave_sum(p);
      int len = min(64, k1 - base);
      for (int j = 0; j < len; ++j) {
        int s = rdl_i(c, j);
        float pj = rdl_f(p, j);
        float2 h = bf2x2(Hp[((size_t)s << 6) + lane]);
        ax0 += pj * h.x; ay0 += pj * h.y;
      }
    }
  }

  float2 hv = bf2x2(Hp[(size_t)n * 64 + lane]);
  ax0 += sp * hv.x; ay0 += sp * hv.y;
  float inv = 1.f / den;
  float2 bv = ((const float2*)bias)[lane];
  float vx = (ax0 + ax1) * inv + bv.x;
  float vy = (ay0 + ay1) * inv + bv.y;
  if (RELU) { vx = fmaxf(vx, 0.f); vy = fmaxf(vy, 0.f); }
  if (OUT_BF16)
    ((unsigned*)outX)[(size_t)n * 64 + lane] = packbf2(vx, vy);
  else
    ((float2*)outX)[(size_t)n * 64 + lane] = make_float2(vx, vy);
}

template<bool RELU, typename IT>
__global__ void gat_fused64(const int* __restrict__ row_ptr,
                            const IT* __restrict__ col,
                            const float* __restrict__ es,
                            const float* __restrict__ ed,
                            const unsigned short* __restrict__ H,
                            const float* __restrict__ bias,
                            float* __restrict__ outX, int N) {
  const int lane = threadIdx.x & 63;
  const int n = blockIdx.x * (blockDim.x >> 6) + (threadIdx.x >> 6);
  if (n >= N) return;

  const int k0 = row_ptr[n];
  const int k1 = row_ptr[n + 1];
  const int deg = k1 - k0;
  const float edd = ed[n];
  const float self_lg = lrelu(es[n] + edd);

  float a0 = 0.f, a1 = 0.f;
  float den, sp;

  if (deg <= 64) {
    int k = k0 + lane;
    bool act = (k < k1);
    int c = act ? (int)col[k] : 0;
    float lg = act ? lrelu(es[c] + edd) : -3.0e38f;
    float m = fmaxf(wave_max(lg), self_lg);
    float p = act ? __expf(lg - m) : 0.f;
    sp = __expf(self_lg - m);
    den = wave_sum(p) + sp;
    int j = 0;
    for (; j + 8 <= deg; j += 8) {
      const unsigned short* rp_[8];
      float pp[8];
      unsigned short uu[8];
#pragma unroll
      for (int q = 0; q < 8; ++q) {
        rp_[q] = H + ((size_t)rdl_i(c, j + q) << 6);
        pp[q] = rdl_f(p, j + q);
      }
#pragma unroll
      for (int q = 0; q < 8; ++q) uu[q] = rp_[q][lane];
#pragma unroll
      for (int q = 0; q < 8; ++q) {
        if (q & 1) a1 += pp[q] * bf1(uu[q]);
        else       a0 += pp[q] * bf1(uu[q]);
      }
    }
    for (; j < deg; ++j) {
      int s = rdl_i(c, j);
      float pj = rdl_f(p, j);
      a0 += pj * bf1(H[((size_t)s << 6) + lane]);
    }
  } else {
    float mloc = self_lg;
    for (int base = k0; base < k1; base += 64) {
      int k = base + lane;
      if (k < k1) mloc = fmaxf(mloc, lrelu(es[(int)col[k]] + edd));
    }
    float m = wave_max(mloc);
    sp = __expf(self_lg - m);
    den = sp;
    for (int base = k0; base < k1; base += 64) {
      int k = base + lane;
      bool act = (k < k1);
      int c = act ? (int)col[k] : 0;
      float p = act ? __expf(lrelu(es[c] + edd) - m) : 0.f;
      den += wave_sum(p);
      int len = min(64, k1 - base);
      for (int j = 0; j < len; ++j) {
        int s = rdl_i(c, j);
        float pj = rdl_f(p, j);
        a0 += pj * bf1(H[((size_t)s << 6) + lane]);
      }
    }
  }

  a0 += sp * bf1(H[(size_t)n * 64 + lane]);
  float v = (a0 + a1) / den + bias[lane];
  if (RELU) v = fmaxf(v, 0.f);
  outX[(size_t)n * 64 + lane] = v;
}

// ---------------------------------------------------------------------------

extern "C" void kernel_launch(void* const* d_in, const int* in_sizes, int n_in,
                              void* d_out, int out_size, void* d_ws, size_t ws_size,
                              hipStream_t stream) {
  const int C_HID = in_sizes[3];            // 128
  const int C_FIN = in_sizes[11];           // 64
  const int C_IN  = in_sizes[2] / C_HID;    // 128
  const int N     = in_sizes[0] / C_IN;     // 50000
  const int E     = in_sizes[1] / 2;        // 1.6M
  const int NPAD  = ((N + 63) / 64) * 64;

  const float* x = (const float*)d_in[0];
  const int* ei  = (const int*)d_in[1];
  const int* src = ei;
  const int* dst = ei + E;

  const float* W0  = (const float*)d_in[2];
  const float* as0 = (const float*)d_in[3];
  const float* ad0 = (const float*)d_in[4];
  const float* b0  = (const float*)d_in[5];
  const float* W1  = (const float*)d_in[6];
  const float* as1 = (const float*)d_in[7];
  const float* ad1 = (const float*)d_in[8];
  const float* b1  = (const float*)d_in[9];
  const float* W2  = (const float*)d_in[10];
  const float* as2 = (const float*)d_in[11];
  const float* ad2 = (const float*)d_in[12];
  const float* b2  = (const float*)d_in[13];

  // Workspace layout (256B aligned)
  char* base = (char*)d_ws;
  size_t off = 0;
  auto alloc = [&](size_t bytes) -> char* {
    char* p = base + off;
    off = (off + bytes + 255) & ~((size_t)255);
    return p;
  };
  const int PBLK = 512;                     // partition blocks
  const int NBK  = (N + 511) >> 9;          // buckets of 512 dst nodes (<=128)
  const int M    = NBK * PBLK;              // offset-matrix size
  const int NCH  = (N + 255) / 256;
  const int MCH  = (M + 255) / 256;
  const int SCH  = (NCH > MCH ? NCH : MCH);

  unsigned short* XB  = (unsigned short*)alloc((size_t)NPAD * C_HID * 2);
  unsigned short* H   = (unsigned short*)alloc((size_t)N * C_HID * 2);
  float* ES    = (float*)alloc((size_t)N * sizeof(float));
  float* ED    = (float*)alloc((size_t)N * sizeof(float));
  int*   RP    = (int*)alloc((size_t)(N + 1) * sizeof(int));
  int*   WP    = (int*)alloc((size_t)N * sizeof(int));
  void*  COL   = (void*)alloc((size_t)E * sizeof(int));   // u16 uses half
  int*   DEG   = (int*)alloc((size_t)N * sizeof(int));
  int*   CSUM  = (int*)alloc((size_t)SCH * sizeof(int));
  int*   HMAT  = (int*)alloc((size_t)M * sizeof(int));
  int*   OFF   = (int*)alloc((size_t)M * sizeof(int));
  int2*  BE    = (int2*)alloc((size_t)E * sizeof(int2));
  (void)ws_size;

  const int wgrid = (N + 3) / 4;
  const int mgrid = NPAD / 64;
  const bool u16 = (N <= 65535);

  // ---- CSR build ----
  if (u16) {
    const int CHUNK = (E + PBLK - 1) / PBLK;
    hist_only<<<PBLK, 256, 0, stream>>>(dst, HMAT, E, NBK, CHUNK);
    scan_partial<<<MCH, 256, 0, stream>>>(HMAT, CSUM, M);
    scan_chunks<<<1, 256, 0, stream>>>(CSUM, MCH);
    scan_final_excl<<<MCH, 256, 0, stream>>>(HMAT, CSUM, OFF, M);
    place_pass<<<PBLK, 256, 0, stream>>>(src, dst, OFF, BE, E, NBK, CHUNK);
    bucket_final<<<NBK, 256, 0, stream>>>(BE, OFF, RP, (unsigned short*)COL,
                                          E, N, NBK, PBLK);
  } else {
    hipMemsetAsync(DEG, 0, (size_t)N * sizeof(int), stream);
    const int ET256 = (E + 255) / 256;
    csr_count<<<ET256, 256, 0, stream>>>(dst, DEG, E);
    scan_partial<<<NCH, 256, 0, stream>>>(DEG, CSUM, N);
    scan_chunks<<<1, 256, 0, stream>>>(CSUM, NCH);
    scan_final<<<NCH, 256, 0, stream>>>(DEG, CSUM, RP, WP, N, E);
    const int NPASS = 8;
    const int range = (N + NPASS - 1) / NPASS;
    csr_scatter_ranged<<<2048, 256, 0, stream>>>(src, dst, WP, (int*)COL, E,
                                                 range, NPASS);
  }

  auto run_layers = [&](auto* col) {
    using IT = typename std::remove_pointer<decltype(col)>::type;
    // ---- Layer 0: x(fp32) -> H(+es/ed) -> XB (relu, bf16) ----
    gemm_mfma<128, true><<<mgrid, 256, 0, stream>>>(x, W0, as0, ad0, H, ES, ED, N);
    gat_fused128<true, true, IT><<<wgrid, 256, 0, stream>>>(RP, col, ES, ED, H, b0, XB, N);
    // ---- Layer 1: XB -> H(+es/ed) -> XB (relu, bf16) ----
    gemm_mfma<128, false><<<mgrid, 256, 0, stream>>>(XB, W1, as1, ad1, H, ES, ED, N);
    gat_fused128<true, true, IT><<<wgrid, 256, 0, stream>>>(RP, col, ES, ED, H, b1, XB, N);
    // ---- Layer 2: XB -> H(+es/ed) -> d_out (no relu, fp32) ----
    gemm_mfma<64, false><<<mgrid, 256, 0, stream>>>(XB, W2, as2, ad2, H, ES, ED, N);
    gat_fused64<false, IT><<<wgrid, 256, 0, stream>>>(RP, col, ES, ED, H, b2,
                                                      (float*)d_out, N);
  };

  if (u16) run_layers((unsigned short*)COL);
  else     run_layers((int*)COL);
  (void)out_size; (void)n_in;
}

// Round 3
// 332.204 us; speedup vs baseline: 1.2298x; 1.0259x over previous
//
#include <hip/hip_runtime.h>
#include <hip/hip_bf16.h>
#include <type_traits>

#define DEVFN __device__ __forceinline__

typedef __attribute__((ext_vector_type(8))) short bfrag;   // 8 bf16 (4 VGPRs)
typedef __attribute__((ext_vector_type(4))) float facc4;   // 4 fp32 acc

DEVFN float lrelu(float v) { return (v >= 0.f) ? v : 0.2f * v; }

// packed bf16x2 (uint) -> 2 floats; elem0 = low 16 bits
DEVFN float2 bf2x2(unsigned u) {
  return make_float2(__uint_as_float(u << 16), __uint_as_float(u & 0xFFFF0000u));
}
DEVFN float bf_lo(unsigned u) { return __uint_as_float(u << 16); }
DEVFN float bf_hi(unsigned u) { return __uint_as_float(u & 0xFFFF0000u); }
DEVFN unsigned short f2bf(float f) {
  __hip_bfloat16 h = __float2bfloat16(f);
  return *reinterpret_cast<unsigned short*>(&h);
}
DEVFN unsigned packbf2(float x, float y) {
  return (unsigned)f2bf(x) | ((unsigned)f2bf(y) << 16);
}

DEVFN float wave_sum(float v) {
#pragma unroll
  for (int o = 1; o < 64; o <<= 1) v += __shfl_xor(v, o, 64);
  return v;
}
DEVFN float wave_max(float v) {
#pragma unroll
  for (int o = 1; o < 64; o <<= 1) v = fmaxf(v, __shfl_xor(v, o, 64));
  return v;
}

// ---------------------------------------------------------------------------
// MFMA GEMM + fused escore + fused weight conversion.
// ---------------------------------------------------------------------------
template<int C, bool A_FP32>
__global__ __launch_bounds__(256) void gemm_mfma(const void* __restrict__ Xin,
                                                 const float* __restrict__ W,
                                                 const float* __restrict__ a_src,
                                                 const float* __restrict__ a_dst,
                                                 unsigned short* __restrict__ H,
                                                 float* __restrict__ es,
                                                 float* __restrict__ ed,
                                                 int N) {
  constexpr int K = 128;
  constexpr int LSTR = K + 8;
  constexpr int NT = C / 16;
  __shared__ unsigned short WsT[C * LSTR];

  const int t = threadIdx.x;
  // stage W (fp32 row-major [k][C]) -> WsT[c][k] bf16, transposed
  for (int i = t; i < K * C; i += 256) {
    int k = i / C;               // C is a power of two -> shift
    int c = i - k * C;
    WsT[c * LSTR + k] = f2bf(W[i]);
  }
  __syncthreads();

  const int wave = t >> 6;
  const int lane = t & 63;
  const int l15 = lane & 15;
  const int quad = lane >> 4;
  const int arow = blockIdx.x * 64 + wave * 16 + l15;
  const bool avalid = arow < N;

  facc4 acc[NT];
#pragma unroll
  for (int i = 0; i < NT; ++i) acc[i] = (facc4){0.f, 0.f, 0.f, 0.f};

#pragma unroll
  for (int ks = 0; ks < 4; ++ks) {
    bfrag a;
    if (A_FP32) {
      if (avalid) {
        const float* xp = (const float*)Xin + (size_t)arow * K + quad * 8 + ks * 32;
        float4 u = *(const float4*)xp;
        float4 v = *(const float4*)(xp + 4);
        a[0] = (short)f2bf(u.x); a[1] = (short)f2bf(u.y);
        a[2] = (short)f2bf(u.z); a[3] = (short)f2bf(u.w);
        a[4] = (short)f2bf(v.x); a[5] = (short)f2bf(v.y);
        a[6] = (short)f2bf(v.z); a[7] = (short)f2bf(v.w);
      } else {
        a = (bfrag){0, 0, 0, 0, 0, 0, 0, 0};
      }
    } else {
      const unsigned short* xp =
          (const unsigned short*)Xin + (size_t)arow * K + quad * 8 + ks * 32;
      a = *(const bfrag*)xp;
    }
#pragma unroll
    for (int ct = 0; ct < NT; ++ct) {
      bfrag b = *(const bfrag*)(&WsT[(ct * 16 + l15) * LSTR + ks * 32 + quad * 8]);
      acc[ct] = __builtin_amdgcn_mfma_f32_16x16x32_bf16(a, b, acc[ct], 0, 0, 0);
    }
  }

  float asv[NT], adv[NT];
#pragma unroll
  for (int ct = 0; ct < NT; ++ct) {
    asv[ct] = a_src[ct * 16 + l15];
    adv[ct] = a_dst[ct * 16 + l15];
  }

  const int orow0 = blockIdx.x * 64 + wave * 16 + quad * 4;
#pragma unroll
  for (int r = 0; r < 4; ++r) {
    const int orow = orow0 + r;
    float ps = 0.f, pd = 0.f;
#pragma unroll
    for (int ct = 0; ct < NT; ++ct) {
      if (orow < N) H[(size_t)orow * C + ct * 16 + l15] = f2bf(acc[ct][r]);
      ps += acc[ct][r] * asv[ct];
      pd += acc[ct][r] * adv[ct];
    }
#pragma unroll
    for (int msk = 1; msk < 16; msk <<= 1) {
      ps += __shfl_xor(ps, msk, 64);
      pd += __shfl_xor(pd, msk, 64);
    }
    if (l15 == 0 && orow < N) { es[orow] = ps; ed[orow] = pd; }
  }
}

// ---------------------------------------------------------------------------
// CSR build (unchanged from R1): radix partition, zero global atomics.
// ---------------------------------------------------------------------------
__global__ void hist_only(const int* __restrict__ dst, int* __restrict__ hmat,
                          int E, int nbk, int chunk) {
  __shared__ int hist[4 * 128];              // 4-way wave replication
  const int t = threadIdx.x;
  for (int i = t; i < 4 * 128; i += 256) hist[i] = 0;
  __syncthreads();
  int* h = &hist[(t >> 6) << 7];
  const int e0 = blockIdx.x * chunk;
  const int e1 = min(E, e0 + chunk);
  for (int e = e0 + t; e < e1; e += 256) {
    atomicAdd(&h[dst[e] >> 9], 1);
  }
  __syncthreads();
  if (t < nbk)
    hmat[t * gridDim.x + blockIdx.x] =
        hist[t] + hist[t + 128] + hist[t + 256] + hist[t + 384];
}

__global__ void scan_partial(const int* __restrict__ in, int* __restrict__ csum, int n) {
  __shared__ int sh[256];
  int i = blockIdx.x * 256 + threadIdx.x;
  sh[threadIdx.x] = (i < n) ? in[i] : 0;
  __syncthreads();
  for (int o = 128; o > 0; o >>= 1) {
    if (threadIdx.x < o) sh[threadIdx.x] += sh[threadIdx.x + o];
    __syncthreads();
  }
  if (threadIdx.x == 0) csum[blockIdx.x] = sh[0];
}

__global__ void scan_chunks(int* __restrict__ csum, int nch) {
  __shared__ int sh[256];
  __shared__ int carry;
  if (threadIdx.x == 0) carry = 0;
  __syncthreads();
  for (int base = 0; base < nch; base += 256) {
    int i = base + threadIdx.x;
    int v = (i < nch) ? csum[i] : 0;
    sh[threadIdx.x] = v;
    __syncthreads();
    for (int o = 1; o < 256; o <<= 1) {
      int t = (threadIdx.x >= o) ? sh[threadIdx.x - o] : 0;
      __syncthreads();
      sh[threadIdx.x] += t;
      __syncthreads();
    }
    if (i < nch) csum[i] = carry + sh[threadIdx.x] - v;
    __syncthreads();
    if (threadIdx.x == 255) carry += sh[255];
    __syncthreads();
  }
}

__global__ void scan_final(const int* __restrict__ deg, const int* __restrict__ csum,
                           int* __restrict__ rp, int* __restrict__ wp, int N, int E) {
  __shared__ int sh[256];
  int i = blockIdx.x * 256 + threadIdx.x;
  int v = (i < N) ? deg[i] : 0;
  sh[threadIdx.x] = v;
  __syncthreads();
  for (int o = 1; o < 256; o <<= 1) {
    int t = (threadIdx.x >= o) ? sh[threadIdx.x - o] : 0;
    __syncthreads();
    sh[threadIdx.x] += t;
    __syncthreads();
  }
  if (i < N) {
    int r = csum[blockIdx.x] + sh[threadIdx.x] - v;
    rp[i] = r;
    wp[i] = r;
  }
  if (blockIdx.x == 0 && threadIdx.x == 0) rp[N] = E;
}

__global__ void scan_final_excl(const int* __restrict__ in, const int* __restrict__ csum,
                                int* __restrict__ out, int n) {
  __shared__ int sh[256];
  int i = blockIdx.x * 256 + threadIdx.x;
  int v = (i < n) ? in[i] : 0;
  sh[threadIdx.x] = v;
  __syncthreads();
  for (int o = 1; o < 256; o <<= 1) {
    int t = (threadIdx.x >= o) ? sh[threadIdx.x - o] : 0;
    __syncthreads();
    sh[threadIdx.x] += t;
    __syncthreads();
  }
  if (i < n) out[i] = csum[blockIdx.x] + sh[threadIdx.x] - v;
}

__global__ void place_pass(const int* __restrict__ src, const int* __restrict__ dst,
                           const int* __restrict__ off, int2* __restrict__ be,
                           int E, int nbk, int chunk) {
  __shared__ int cur[128];
  const int t = threadIdx.x;
  if (t < nbk) cur[t] = off[t * gridDim.x + blockIdx.x];
  __syncthreads();
  const int e0 = blockIdx.x * chunk;
  const int e1 = min(E, e0 + chunk);
  for (int e = e0 + t; e < e1; e += 256) {
    int d = dst[e];
    int s = src[e];
    int p = atomicAdd(&cur[d >> 9], 1);
    be[p] = make_int2(s, d);
  }
}

__global__ void bucket_final(const int2* __restrict__ be, const int* __restrict__ off,
                             int* __restrict__ rp, unsigned short* __restrict__ col,
                             int E, int N, int nbk, int pblk) {
  __shared__ int cur[512];
  __shared__ int ps[256];
  const int b = blockIdx.x;
  const int n0 = b << 9;
  const int cnt = min(512, N - n0);
  const int t = threadIdx.x;
  for (int i = t; i < cnt; i += 256) cur[i] = 0;
  __syncthreads();
  const int e0 = off[b * pblk];
  const int e1 = (b + 1 < nbk) ? off[(b + 1) * pblk] : E;
  for (int e = e0 + t; e < e1; e += 256) {
    int2 sd = be[e];
    atomicAdd(&cur[sd.y - n0], 1);
  }
  __syncthreads();
  const int i0 = 2 * t, i1 = 2 * t + 1;
  const int v0 = (i0 < cnt) ? cur[i0] : 0;
  const int v1 = (i1 < cnt) ? cur[i1] : 0;
  ps[t] = v0 + v1;
  __syncthreads();
  for (int o = 1; o < 256; o <<= 1) {
    int u = (t >= o) ? ps[t - o] : 0;
    __syncthreads();
    ps[t] += u;
    __syncthreads();
  }
  const int base = e0 + ps[t] - (v0 + v1);
  if (i0 < cnt) { rp[n0 + i0] = base;      cur[i0] = base; }
  if (i1 < cnt) { rp[n0 + i1] = base + v0; cur[i1] = base + v0; }
  if (b == nbk - 1 && t == 0) rp[N] = E;
  __syncthreads();
  for (int e = e0 + t; e < e1; e += 256) {
    int2 sd = be[e];
    int p = atomicAdd(&cur[sd.y - n0], 1);
    col[p] = (unsigned short)sd.x;
  }
}

__global__ void csr_scatter_ranged(const int* __restrict__ src,
                                   const int* __restrict__ dst,
                                   int* __restrict__ wp, int* __restrict__ col,
                                   int E, int range, int npass) {
  const int stride = gridDim.x * blockDim.x;
  const int gid = blockIdx.x * blockDim.x + threadIdx.x;
  for (int pass = 0; pass < npass; ++pass) {
    const int lo = pass * range;
    const int hi = lo + range;
    for (int e = gid; e < E; e += stride) {
      int d = dst[e];
      if (d >= lo && d < hi) {
        int p = atomicAdd(wp + d, 1);
        col[p] = src[e];
      }
    }
  }
}

__global__ void csr_count(const int* __restrict__ dst, int* __restrict__ deg, int E) {
  int e = blockIdx.x * blockDim.x + threadIdx.x;
  if (e < E) atomicAdd(deg + dst[e], 1);
}

// ---------------------------------------------------------------------------
// Fused GAT edge stage, grouped-gather version.
// C=128: wave = 4 groups x 16 lanes; one dwordx4 per group -> 4 edges/VMEM.
// C=64 : wave = 8 groups x 8 lanes  -> 8 edges/VMEM.
// Each lane accumulates 8 channels; cross-group shfl_xor reduce at the end.
// Tail-free hot loop: clamp broadcast lane, rely on p=0 padding.
// ---------------------------------------------------------------------------
template<bool RELU, typename IT>
__global__ void gat_fused128(const int* __restrict__ row_ptr,
                             const IT* __restrict__ col,
                             const float* __restrict__ es,
                             const float* __restrict__ ed,
                             const unsigned short* __restrict__ H,
                             const float* __restrict__ bias,
                             void* __restrict__ outX, int N) {
  const int lane = threadIdx.x & 63;
  const int n = blockIdx.x * (blockDim.x >> 6) + (threadIdx.x >> 6);
  if (n >= N) return;

  const int g4 = lane >> 4;       // group 0..3
  const int l15 = lane & 15;

  const int k0 = row_ptr[n];
  const int k1 = row_ptr[n + 1];
  const int deg = k1 - k0;
  const float edd = ed[n];
  const float self_lg = lrelu(es[n] + edd);

  const char* Hb = (const char*)H;
  float acc[8];
#pragma unroll
  for (int i = 0; i < 8; ++i) acc[i] = 0.f;
  float den, sp;

  if (deg <= 64) {
    int k = k0 + lane;
    bool act = (k < k1);
    int c = act ? (int)col[k] : 0;
    float lg = act ? lrelu(es[c] + edd) : -3.0e38f;
    float m = fmaxf(wave_max(lg), self_lg);
    float p = act ? __expf(lg - m) : 0.f;
    sp = __expf(self_lg - m);
    den = wave_sum(p) + sp;
    for (int j = 0; j < deg; j += 8) {
      int i0 = min(j + g4, 63);
      int i1 = min(j + 4 + g4, 63);
      int c0 = __shfl(c, i0);
      int c1 = __shfl(c, i1);
      float p0 = __shfl(p, i0);
      float p1 = __shfl(p, i1);
      uint4 v0 = *(const uint4*)(Hb + (((size_t)c0 << 8) + l15 * 16));
      uint4 v1 = *(const uint4*)(Hb + (((size_t)c1 << 8) + l15 * 16));
      acc[0] += p0 * bf_lo(v0.x); acc[1] += p0 * bf_hi(v0.x);
      acc[2] += p0 * bf_lo(v0.y); acc[3] += p0 * bf_hi(v0.y);
      acc[4] += p0 * bf_lo(v0.z); acc[5] += p0 * bf_hi(v0.z);
      acc[6] += p0 * bf_lo(v0.w); acc[7] += p0 * bf_hi(v0.w);
      acc[0] += p1 * bf_lo(v1.x); acc[1] += p1 * bf_hi(v1.x);
      acc[2] += p1 * bf_lo(v1.y); acc[3] += p1 * bf_hi(v1.y);
      acc[4] += p1 * bf_lo(v1.z); acc[5] += p1 * bf_hi(v1.z);
      acc[6] += p1 * bf_lo(v1.w); acc[7] += p1 * bf_hi(v1.w);
    }
  } else {
    float mloc = self_lg;
    for (int base = k0; base < k1; base += 64) {
      int k = base + lane;
      if (k < k1) mloc = fmaxf(mloc, lrelu(es[(int)col[k]] + edd));
    }
    float m = wave_max(mloc);
    sp = __expf(self_lg - m);
    den = sp;
    for (int base = k0; base < k1; base += 64) {
      int k = base + lane;
      bool act = (k < k1);
      int c = act ? (int)col[k] : 0;
      float p = act ? __expf(lrelu(es[c] + edd) - m) : 0.f;
      den += wave_sum(p);
      int len = min(64, k1 - base);
      for (int j = 0; j < len; j += 8) {
        int i0 = min(j + g4, 63);
        int i1 = min(j + 4 + g4, 63);
        int c0 = __shfl(c, i0);
        int c1 = __shfl(c, i1);
        float p0 = __shfl(p, i0);
        float p1 = __shfl(p, i1);
        uint4 v0 = *(const uint4*)(Hb + (((size_t)c0 << 8) + l15 * 16));
        uint4 v1 = *(const uint4*)(Hb + (((size_t)c1 << 8) + l15 * 16));
        acc[0] += p0 * bf_lo(v0.x); acc[1] += p0 * bf_hi(v0.x);
        acc[2] += p0 * bf_lo(v0.y); acc[3] += p0 * bf_hi(v0.y);
        acc[4] += p0 * bf_lo(v0.z); acc[5] += p0 * bf_hi(v0.z);
        acc[6] += p0 * bf_lo(v0.w); acc[7] += p0 * bf_hi(v0.w);
        acc[0] += p1 * bf_lo(v1.x); acc[1] += p1 * bf_hi(v1.x);
        acc[2] += p1 * bf_lo(v1.y); acc[3] += p1 * bf_hi(v1.y);
        acc[4] += p1 * bf_lo(v1.z); acc[5] += p1 * bf_hi(v1.z);
        acc[6] += p1 * bf_lo(v1.w); acc[7] += p1 * bf_hi(v1.w);
      }
    }
  }

  // reduce across the 4 groups (lanes with equal l15 hold the same channels)
#pragma unroll
  for (int i = 0; i < 8; ++i) {
    acc[i] += __shfl_xor(acc[i], 16, 64);
    acc[i] += __shfl_xor(acc[i], 32, 64);
  }

  // self-loop + epilogue (all lanes compute; group 0 stores)
  uint4 hv = *(const uint4*)(Hb + (((size_t)n << 8) + l15 * 16));
  acc[0] += sp * bf_lo(hv.x); acc[1] += sp * bf_hi(hv.x);
  acc[2] += sp * bf_lo(hv.y); acc[3] += sp * bf_hi(hv.y);
  acc[4] += sp * bf_lo(hv.z); acc[5] += sp * bf_hi(hv.z);
  acc[6] += sp * bf_lo(hv.w); acc[7] += sp * bf_hi(hv.w);

  float inv = 1.f / den;
  float4 bv0 = *(const float4*)(bias + l15 * 8);
  float4 bv1 = *(const float4*)(bias + l15 * 8 + 4);
  float o0 = acc[0] * inv + bv0.x, o1 = acc[1] * inv + bv0.y;
  float o2 = acc[2] * inv + bv0.z, o3 = acc[3] * inv + bv0.w;
  float o4 = acc[4] * inv + bv1.x, o5 = acc[5] * inv + bv1.y;
  float o6 = acc[6] * inv + bv1.z, o7 = acc[7] * inv + bv1.w;
  if (RELU) {
    o0 = fmaxf(o0, 0.f); o1 = fmaxf(o1, 0.f); o2 = fmaxf(o2, 0.f);
    o3 = fmaxf(o3, 0.f); o4 = fmaxf(o4, 0.f); o5 = fmaxf(o5, 0.f);
    o6 = fmaxf(o6, 0.f); o7 = fmaxf(o7, 0.f);
  }
  if (g4 == 0) {
    uint4 w;
    w.x = packbf2(o0, o1); w.y = packbf2(o2, o3);
    w.z = packbf2(o4, o5); w.w = packbf2(o6, o7);
    *(uint4*)((char*)outX + (((size_t)n << 8) + l15 * 16)) = w;
  }
}

template<bool RELU, typename IT>
__global__ void gat_fused64(const int* __restrict__ row_ptr,
                            const IT* __restrict__ col,
                            const float* __restrict__ es,
                            const float* __restrict__ ed,
                            const unsigned short* __restrict__ H,
                            const float* __restrict__ bias,
                            float* __restrict__ outX, int N) {
  const int lane = threadIdx.x & 63;
  const int n = blockIdx.x * (blockDim.x >> 6) + (threadIdx.x >> 6);
  if (n >= N) return;

  const int g8 = lane >> 3;       // group 0..7
  const int l8 = lane & 7;

  const int k0 = row_ptr[n];
  const int k1 = row_ptr[n + 1];
  const int deg = k1 - k0;
  const float edd = ed[n];
  const float self_lg = lrelu(es[n] + edd);

  const char* Hb = (const char*)H;
  float acc[8];
#pragma unroll
  for (int i = 0; i < 8; ++i) acc[i] = 0.f;
  float den, sp;

  if (deg <= 64) {
    int k = k0 + lane;
    bool act = (k < k1);
    int c = act ? (int)col[k] : 0;
    float lg = act ? lrelu(es[c] + edd) : -3.0e38f;
    float m = fmaxf(wave_max(lg), self_lg);
    float p = act ? __expf(lg - m) : 0.f;
    sp = __expf(self_lg - m);
    den = wave_sum(p) + sp;
    for (int j = 0; j < deg; j += 8) {
      int i0 = min(j + g8, 63);
      int c0 = __shfl(c, i0);
      float p0 = __shfl(p, i0);
      uint4 v0 = *(const uint4*)(Hb + (((size_t)c0 << 7) + l8 * 16));
      acc[0] += p0 * bf_lo(v0.x); acc[1] += p0 * bf_hi(v0.x);
      acc[2] += p0 * bf_lo(v0.y); acc[3] += p0 * bf_hi(v0.y);
      acc[4] += p0 * bf_lo(v0.z); acc[5] += p0 * bf_hi(v0.z);
      acc[6] += p0 * bf_lo(v0.w); acc[7] += p0 * bf_hi(v0.w);
    }
  } else {
    float mloc = self_lg;
    for (int base = k0; base < k1; base += 64) {
      int k = base + lane;
      if (k < k1) mloc = fmaxf(mloc, lrelu(es[(int)col[k]] + edd));
    }
    float m = wave_max(mloc);
    sp = __expf(self_lg - m);
    den = sp;
    for (int base = k0; base < k1; base += 64) {
      int k = base + lane;
      bool act = (k < k1);
      int c = act ? (int)col[k] : 0;
      float p = act ? __expf(lrelu(es[c] + edd) - m) : 0.f;
      den += wave_sum(p);
      int len = min(64, k1 - base);
      for (int j = 0; j < len; j += 8) {
        int i0 = min(j + g8, 63);
        int c0 = __shfl(c, i0);
        float p0 = __shfl(p, i0);
        uint4 v0 = *(const uint4*)(Hb + (((size_t)c0 << 7) + l8 * 16));
        acc[0] += p0 * bf_lo(v0.x); acc[1] += p0 * bf_hi(v0.x);
        acc[2] += p0 * bf_lo(v0.y); acc[3] += p0 * bf_hi(v0.y);
        acc[4] += p0 * bf_lo(v0.z); acc[5] += p0 * bf_hi(v0.z);
        acc[6] += p0 * bf_lo(v0.w); acc[7] += p0 * bf_hi(v0.w);
      }
    }
  }

  // reduce across the 8 groups
#pragma unroll
  for (int i = 0; i < 8; ++i) {
    acc[i] += __shfl_xor(acc[i], 8, 64);
    acc[i] += __shfl_xor(acc[i], 16, 64);
    acc[i] += __shfl_xor(acc[i], 32, 64);
  }

  // self-loop + epilogue
  uint4 hv = *(const uint4*)(Hb + (((size_t)n << 7) + l8 * 16));
  acc[0] += sp * bf_lo(hv.x); acc[1] += sp * bf_hi(hv.x);
  acc[2] += sp * bf_lo(hv.y); acc[3] += sp * bf_hi(hv.y);
  acc[4] += sp * bf_lo(hv.z); acc[5] += sp * bf_hi(hv.z);
  acc[6] += sp * bf_lo(hv.w); acc[7] += sp * bf_hi(hv.w);

  float inv = 1.f / den;
  float4 bv0 = *(const float4*)(bias + l8 * 8);
  float4 bv1 = *(const float4*)(bias + l8 * 8 + 4);
  float4 w0, w1;
  w0.x = acc[0] * inv + bv0.x; w0.y = acc[1] * inv + bv0.y;
  w0.z = acc[2] * inv + bv0.z; w0.w = acc[3] * inv + bv0.w;
  w1.x = acc[4] * inv + bv1.x; w1.y = acc[5] * inv + bv1.y;
  w1.z = acc[6] * inv + bv1.z; w1.w = acc[7] * inv + bv1.w;
  if (RELU) {
    w0.x = fmaxf(w0.x, 0.f); w0.y = fmaxf(w0.y, 0.f);
    w0.z = fmaxf(w0.z, 0.f); w0.w = fmaxf(w0.w, 0.f);
    w1.x = fmaxf(w1.x, 0.f); w1.y = fmaxf(w1.y, 0.f);
    w1.z = fmaxf(w1.z, 0.f); w1.w = fmaxf(w1.w, 0.f);
  }
  if (g8 == 0) {
    char* op = (char*)outX + (((size_t)n << 8) + l8 * 32);
    *(float4*)op = w0;
    *(float4*)(op + 16) = w1;
  }
}

// ---------------------------------------------------------------------------

extern "C" void kernel_launch(void* const* d_in, const int* in_sizes, int n_in,
                              void* d_out, int out_size, void* d_ws, size_t ws_size,
                              hipStream_t stream) {
  const int C_HID = in_sizes[3];            // 128
  const int C_FIN = in_sizes[11];           // 64
  const int C_IN  = in_sizes[2] / C_HID;    // 128
  const int N     = in_sizes[0] / C_IN;     // 50000
  const int E     = in_sizes[1] / 2;        // 1.6M
  const int NPAD  = ((N + 63) / 64) * 64;

  const float* x = (const float*)d_in[0];
  const int* ei  = (const int*)d_in[1];
  const int* src = ei;
  const int* dst = ei + E;

  const float* W0  = (const float*)d_in[2];
  const float* as0 = (const float*)d_in[3];
  const float* ad0 = (const float*)d_in[4];
  const float* b0  = (const float*)d_in[5];
  const float* W1  = (const float*)d_in[6];
  const float* as1 = (const float*)d_in[7];
  const float* ad1 = (const float*)d_in[8];
  const float* b1  = (const float*)d_in[9];
  const float* W2  = (const float*)d_in[10];
  const float* as2 = (const float*)d_in[11];
  const float* ad2 = (const float*)d_in[12];
  const float* b2  = (const float*)d_in[13];

  // Workspace layout (256B aligned)
  char* base = (char*)d_ws;
  size_t off = 0;
  auto alloc = [&](size_t bytes) -> char* {
    char* p = base + off;
    off = (off + bytes + 255) & ~((size_t)255);
    return p;
  };
  const int PBLK = 512;                     // partition blocks
  const int NBK  = (N + 511) >> 9;          // buckets of 512 dst nodes (<=128)
  const int M    = NBK * PBLK;              // offset-matrix size
  const int NCH  = (N + 255) / 256;
  const int MCH  = (M + 255) / 256;
  const int SCH  = (NCH > MCH ? NCH : MCH);

  unsigned short* XB  = (unsigned short*)alloc((size_t)NPAD * C_HID * 2);
  unsigned short* H   = (unsigned short*)alloc((size_t)N * C_HID * 2);
  float* ES    = (float*)alloc((size_t)N * sizeof(float));
  float* ED    = (float*)alloc((size_t)N * sizeof(float));
  int*   RP    = (int*)alloc((size_t)(N + 1) * sizeof(int));
  int*   WP    = (int*)alloc((size_t)N * sizeof(int));
  void*  COL   = (void*)alloc((size_t)E * sizeof(int));   // u16 uses half
  int*   DEG   = (int*)alloc((size_t)N * sizeof(int));
  int*   CSUM  = (int*)alloc((size_t)SCH * sizeof(int));
  int*   HMAT  = (int*)alloc((size_t)M * sizeof(int));
  int*   OFF   = (int*)alloc((size_t)M * sizeof(int));
  int2*  BE    = (int2*)alloc((size_t)E * sizeof(int2));
  (void)ws_size;

  const int wgrid = (N + 3) / 4;
  const int mgrid = NPAD / 64;
  const bool u16 = (N <= 65535);

  // ---- CSR build ----
  if (u16) {
    const int CHUNK = (E + PBLK - 1) / PBLK;
    hist_only<<<PBLK, 256, 0, stream>>>(dst, HMAT, E, NBK, CHUNK);
    scan_partial<<<MCH, 256, 0, stream>>>(HMAT, CSUM, M);
    scan_chunks<<<1, 256, 0, stream>>>(CSUM, MCH);
    scan_final_excl<<<MCH, 256, 0, stream>>>(HMAT, CSUM, OFF, M);
    place_pass<<<PBLK, 256, 0, stream>>>(src, dst, OFF, BE, E, NBK, CHUNK);
    bucket_final<<<NBK, 256, 0, stream>>>(BE, OFF, RP, (unsigned short*)COL,
                                          E, N, NBK, PBLK);
  } else {
    hipMemsetAsync(DEG, 0, (size_t)N * sizeof(int), stream);
    const int ET256 = (E + 255) / 256;
    csr_count<<<ET256, 256, 0, stream>>>(dst, DEG, E);
    scan_partial<<<NCH, 256, 0, stream>>>(DEG, CSUM, N);
    scan_chunks<<<1, 256, 0, stream>>>(CSUM, NCH);
    scan_final<<<NCH, 256, 0, stream>>>(DEG, CSUM, RP, WP, N, E);
    const int NPASS = 8;
    const int range = (N + NPASS - 1) / NPASS;
    csr_scatter_ranged<<<2048, 256, 0, stream>>>(src, dst, WP, (int*)COL, E,
                                                 range, NPASS);
  }

  auto run_layers = [&](auto* col) {
    using IT = typename std::remove_pointer<decltype(col)>::type;
    // ---- Layer 0: x(fp32) -> H(+es/ed) -> XB (relu, bf16) ----
    gemm_mfma<128, true><<<mgrid, 256, 0, stream>>>(x, W0, as0, ad0, H, ES, ED, N);
    gat_fused128<true, IT><<<wgrid, 256, 0, stream>>>(RP, col, ES, ED, H, b0, XB, N);
    // ---- Layer 1: XB -> H(+es/ed) -> XB (relu, bf16) ----
    gemm_mfma<128, false><<<mgrid, 256, 0, stream>>>(XB, W1, as1, ad1, H, ES, ED, N);
    gat_fused128<true, IT><<<wgrid, 256, 0, stream>>>(RP, col, ES, ED, H, b1, XB, N);
    // ---- Layer 2: XB -> H(+es/ed) -> d_out (no relu, fp32) ----
    gemm_mfma<64, false><<<mgrid, 256, 0, stream>>>(XB, W2, as2, ad2, H, ES, ED, N);
    gat_fused64<false, IT><<<wgrid, 256, 0, stream>>>(RP, col, ES, ED, H, b2,
                                                      (float*)d_out, N);
  };

  if (u16) run_layers((unsigned short*)COL);
  else     run_layers((int*)COL);
  (void)out_size; (void)n_in;
}